// Round 7
// baseline (5196.507 us; speedup 1.0000x reference)
//
#include <hip/hip_runtime.h>
#include <hip/hip_bf16.h>

#define DH 20            // hidden width
#define SCAN_CHUNKS 1024

typedef __attribute__((ext_vector_type(2))) double double2v;

// ---------------- setup kernels ----------------

// deg arrays are zeroed by hipMemsetAsync; counts EXCLUDE self-loop.
__global__ void count_deg(const int* __restrict__ src, const int* __restrict__ dst,
                          int* __restrict__ out_deg, int* __restrict__ in_deg, int E) {
    int e = blockIdx.x * blockDim.x + threadIdx.x;
    if (e < E) {
        atomicAdd(&out_deg[src[e]], 1);
        atomicAdd(&in_deg[dst[e]], 1);
    }
}

// norm = (deg+1)^-1/2  (self-loop included here)
__global__ void compute_norm(const int* __restrict__ out_deg, const int* __restrict__ in_deg,
                             double* __restrict__ dout, double* __restrict__ din, int n) {
    int i = blockIdx.x * blockDim.x + threadIdx.x;
    if (i < n) {
        dout[i] = 1.0 / sqrt((double)(out_deg[i] + 1));
        din[i]  = 1.0 / sqrt((double)(in_deg[i] + 1));
    }
}

// ---- parallel row_ptr build: chunk sums -> scan -> fill ----

__global__ void chunk_sums(const int* __restrict__ in_deg, int* __restrict__ cs, int n_nodes) {
    int w    = (blockIdx.x * blockDim.x + threadIdx.x) >> 6;   // wave = chunk
    int lane = threadIdx.x & 63;
    if (w >= SCAN_CHUNKS) return;
    int chunk = (n_nodes + SCAN_CHUNKS - 1) / SCAN_CHUNKS;
    int lo = w * chunk;
    int hi = lo + chunk; if (hi > n_nodes) hi = n_nodes;
    int s = 0;
    for (int i = lo + lane; i < hi; i += 64) s += in_deg[i];
#pragma unroll
    for (int off = 32; off; off >>= 1) s += __shfl_xor(s, off, 64);
    if (lane == 0) cs[w] = s;
}

__global__ void scan_chunks(int* __restrict__ cs) {
    __shared__ int lds[SCAN_CHUNKS];
    int t = threadIdx.x;
    int v = cs[t];
    lds[t] = v;
    __syncthreads();
    for (int off = 1; off < SCAN_CHUNKS; off <<= 1) {
        int u = (t >= off) ? lds[t - off] : 0;
        __syncthreads();
        lds[t] += u;
        __syncthreads();
    }
    cs[t] = lds[t] - v;   // exclusive prefix
}

__global__ void fill_rowptr(const int* __restrict__ in_deg, const int* __restrict__ cs,
                            int* __restrict__ row_ptr, int* __restrict__ cursor,
                            int n_nodes, int n_edges) {
    int w    = (blockIdx.x * blockDim.x + threadIdx.x) >> 6;   // wave = chunk
    int lane = threadIdx.x & 63;
    if (w >= SCAN_CHUNKS) return;
    int chunk = (n_nodes + SCAN_CHUNKS - 1) / SCAN_CHUNKS;
    int lo = w * chunk;
    int hi = lo + chunk; if (hi > n_nodes) hi = n_nodes;
    int run = cs[w];
    for (int base = lo; base < hi; base += 64) {
        int i = base + lane;
        int d = (i < hi) ? in_deg[i] : 0;
        int incl = d;
#pragma unroll
        for (int off = 1; off < 64; off <<= 1) {
            int t = __shfl_up(incl, off, 64);
            if (lane >= off) incl += t;
        }
        int excl = run + incl - d;
        if (i < hi) { row_ptr[i] = excl; cursor[i] = excl; }
        run += __shfl(incl, 63, 64);
    }
    if (w == 0 && lane == 0) row_ptr[n_nodes] = n_edges;
}

__global__ void fill_csr(const int* __restrict__ src, const int* __restrict__ dst,
                         int* __restrict__ cursor, int* __restrict__ col, int E) {
    int e = blockIdx.x * blockDim.x + threadIdx.x;
    if (e < E) {
        int slot = atomicAdd(&cursor[dst[e]], 1);
        col[slot] = src[e];
    }
}

// ---------------- layer kernels ----------------
// x is stored feature-blocked: xA = x[:,0:8], xB = x[:,8:16], xC = x[:,16:20].
// Each block (<=3.2 MB) fits a per-XCD L2, so random gathers stay L2-resident.

// x0[n] = feat[n] * dout[n]   (layer 0 input is N x 1)
__global__ void compute_x0(const float* __restrict__ feat, const double* __restrict__ dout,
                           double* __restrict__ x0, int n) {
    int i = blockIdx.x * blockDim.x + threadIdx.x;
    if (i < n) x0[i] = (double)feat[i] * dout[i];
}

// layer 0: scalar gather, writes blocked x
__global__ __launch_bounds__(256) void layer_start(
        const double* __restrict__ x0, const int* __restrict__ row_ptr,
        const int* __restrict__ col, const double* __restrict__ din,
        const double* __restrict__ dout, const float* __restrict__ W,
        const float* __restrict__ b, float* __restrict__ xA,
        float* __restrict__ xB, float* __restrict__ xC, int n_nodes) {
    int n    = (blockIdx.x * blockDim.x + threadIdx.x) >> 6;   // one wave per node
    int lane = threadIdx.x & 63;
    if (n >= n_nodes) return;
    double a = (lane == 0) ? x0[n] : 0.0;   // self loop
    int e0 = row_ptr[n], e1 = row_ptr[n + 1];
    for (int e = e0 + lane; e < e1; e += 64)
        a += x0[__builtin_nontemporal_load(&col[e])];
#pragma unroll
    for (int off = 32; off > 0; off >>= 1)
        a += __shfl_xor(a, off, 64);
    if (lane < DH) {
        double v = a * din[n] * (double)W[lane] + (double)b[lane];
        float r = fmaxf((float)v, 0.0f);
        float xv = (float)((double)r * dout[n]);
        if (lane < 8)       xA[(size_t)n * 8 + lane] = xv;
        else if (lane < 16) xB[(size_t)n * 8 + lane - 8] = xv;
        else                xC[(size_t)n * 4 + lane - 16] = xv;
    }
}

// gather an 8-feature block: one wave per node; lane = 2*ep + q covers 32 edges
// per instruction (2 instrs = 64 edges). fp64 sum -> g block (nontemporal store).
__global__ __launch_bounds__(256) void gather8(
        const float* __restrict__ xblk, const int* __restrict__ row_ptr,
        const int* __restrict__ col, double* __restrict__ gout, int n_nodes) {
    int n    = (blockIdx.x * blockDim.x + threadIdx.x) >> 6;
    int lane = threadIdx.x & 63;
    if (n >= n_nodes) return;
    int ep = lane >> 1, q = lane & 1;          // edge slot, float4 half of the 32 B row
    const float4* __restrict__ x4 = (const float4*)xblk;
    int e0 = row_ptr[n], e1 = row_ptr[n + 1];
    int ci = -1;
    if (e0 + lane < e1) ci = __builtin_nontemporal_load(&col[e0 + lane]);
    int s0 = __shfl(ci, ep, 64);               // edge position e0+ep
    int s1 = __shfl(ci, ep + 32, 64);          // edge position e0+ep+32
    float4 z = {0.0f, 0.0f, 0.0f, 0.0f};
    float4 vs = (ep == 0) ? x4[(size_t)n * 2 + q] : z;    // self loop on slot 0
    float4 v0 = (s0 >= 0) ? x4[(size_t)s0 * 2 + q] : z;
    float4 v1 = (s1 >= 0) ? x4[(size_t)s1 * 2 + q] : z;
    double a0 = (double)vs.x + (double)v0.x + (double)v1.x;
    double a1 = (double)vs.y + (double)v0.y + (double)v1.y;
    double a2 = (double)vs.z + (double)v0.z + (double)v1.z;
    double a3 = (double)vs.w + (double)v0.w + (double)v1.w;
    if (e1 - e0 > 64) {                        // rare tail (Poisson(32): ~never)
        for (int e = e0 + 64 + ep; e < e1; e += 32) {
            int s = col[e];
            float4 v = x4[(size_t)s * 2 + q];
            a0 += (double)v.x; a1 += (double)v.y; a2 += (double)v.z; a3 += (double)v.w;
        }
    }
#pragma unroll
    for (int off = 2; off <= 32; off <<= 1) {  // fold over ep (q preserved)
        a0 += __shfl_xor(a0, off, 64);
        a1 += __shfl_xor(a1, off, 64);
        a2 += __shfl_xor(a2, off, 64);
        a3 += __shfl_xor(a3, off, 64);
    }
    if (lane < 2) {                            // lane q holds features 4q..4q+3
        double2v d01, d23;
        d01.x = a0; d01.y = a1; d23.x = a2; d23.y = a3;
        double2v* go = (double2v*)(gout + (size_t)n * 8 + (size_t)lane * 4);
        __builtin_nontemporal_store(d01, go);
        __builtin_nontemporal_store(d23, go + 1);
    }
}

// gather the 4-feature block (lane = edge slot, 64 edges per instruction) and
// fuse the full 20x20 fp64 matvec (gA/gB read back as wave-uniform scalar loads),
// relu/norm, and the blocked store of the next layer's x (or d_out for mode 1).
__global__ __launch_bounds__(256) void gather4_matvec(
        const float* __restrict__ xC, const int* __restrict__ row_ptr,
        const int* __restrict__ col, const double* __restrict__ gA,
        const double* __restrict__ gB, const double* __restrict__ din,
        const double* __restrict__ dout, const float* __restrict__ W,
        const float* __restrict__ b, float* __restrict__ oA,
        float* __restrict__ oB, float* __restrict__ oC,
        float* __restrict__ oFull, int n_nodes, int mode) {
    __shared__ float Wl[DH * DH];
    for (int i = threadIdx.x; i < DH * DH; i += blockDim.x) Wl[i] = W[i];
    __syncthreads();

    int n    = (blockIdx.x * blockDim.x + threadIdx.x) >> 6;
    int lane = threadIdx.x & 63;
    if (n >= n_nodes) return;
    n = __builtin_amdgcn_readfirstlane(n);     // uniform -> scalar loads for g/row_ptr

    const float4* __restrict__ x4 = (const float4*)xC;   // 16 B rows
    int e0 = row_ptr[n], e1 = row_ptr[n + 1];
    int ci = -1;
    if (e0 + lane < e1) ci = __builtin_nontemporal_load(&col[e0 + lane]);
    float4 z = {0.0f, 0.0f, 0.0f, 0.0f};
    float4 vs = (lane == 0) ? x4[n] : z;       // self loop
    float4 v0 = (ci >= 0) ? x4[(size_t)ci] : z;
    double a0 = (double)vs.x + (double)v0.x;
    double a1 = (double)vs.y + (double)v0.y;
    double a2 = (double)vs.z + (double)v0.z;
    double a3 = (double)vs.w + (double)v0.w;
    if (e1 - e0 > 64) {
        for (int e = e0 + 64 + lane; e < e1; e += 64) {
            int s = col[e];
            float4 v = x4[(size_t)s];
            a0 += (double)v.x; a1 += (double)v.y; a2 += (double)v.z; a3 += (double)v.w;
        }
    }
#pragma unroll
    for (int off = 1; off <= 32; off <<= 1) {  // full fold: all lanes get gC[0..3]
        a0 += __shfl_xor(a0, off, 64);
        a1 += __shfl_xor(a1, off, 64);
        a2 += __shfl_xor(a2, off, 64);
        a3 += __shfl_xor(a3, off, 64);
    }

    // matvec: out_j = sum_k g_k W[k][j]; gA/gB rows are wave-uniform (scalar loads)
    int j = (lane < DH) ? lane : 0;
    double acc = 0.0;
    const double* __restrict__ ga = gA + (size_t)n * 8;
    const double* __restrict__ gb = gB + (size_t)n * 8;
#pragma unroll
    for (int k = 0; k < 8; ++k) acc += ga[k] * (double)Wl[k * DH + j];
#pragma unroll
    for (int k = 0; k < 8; ++k) acc += gb[k] * (double)Wl[(k + 8) * DH + j];
    acc += a0 * (double)Wl[16 * DH + j] + a1 * (double)Wl[17 * DH + j]
         + a2 * (double)Wl[18 * DH + j] + a3 * (double)Wl[19 * DH + j];

    if (lane < DH) {
        double v = acc * din[n] + (double)b[lane];
        if (mode == 0) {
            float r = fmaxf((float)v, 0.0f);
            float xv = (float)((double)r * dout[n]);
            if (lane < 8)       oA[(size_t)n * 8 + lane] = xv;
            else if (lane < 16) oB[(size_t)n * 8 + lane - 8] = xv;
            else                oC[(size_t)n * 4 + lane - 16] = xv;
        } else {
            oFull[(size_t)n * DH + lane] = (float)v;
        }
    }
}

// ---------------- launch ----------------

static inline size_t align256(size_t x) { return (x + 255) & ~(size_t)255; }

extern "C" void kernel_launch(void* const* d_in, const int* in_sizes, int n_in,
                              void* d_out, int out_size, void* d_ws, size_t ws_size,
                              hipStream_t stream) {
    const float* feat    = (const float*)d_in[0];
    const float* W_start = (const float*)d_in[1];
    const float* b_start = (const float*)d_in[2];
    const float* W_mid   = (const float*)d_in[3];
    const float* b_mid   = (const float*)d_in[4];
    const float* W_final = (const float*)d_in[5];
    const float* b_final = (const float*)d_in[6];
    const int*   src     = (const int*)d_in[7];
    const int*   dst     = (const int*)d_in[8];

    const int N = in_sizes[0];              // 100000
    const int E = in_sizes[7];              // 3200000
    const int L = in_sizes[3] / (DH * DH);  // 18 mid layers

    // workspace carve-up
    char* p = (char*)d_ws;
    double* dout_d = (double*)p; p += align256(sizeof(double) * N);
    double* din_d  = (double*)p; p += align256(sizeof(double) * N);
    double* x0     = (double*)p; p += align256(sizeof(double) * N);
    int* out_deg   = (int*)p;    p += align256(sizeof(int) * N);
    int* in_deg    = (int*)p;    p += align256(sizeof(int) * N);
    int* row_ptr   = (int*)p;    p += align256(sizeof(int) * (N + 1));
    int* cursor    = (int*)p;    p += align256(sizeof(int) * N);
    int* cs        = (int*)p;    p += align256(sizeof(int) * SCAN_CHUNKS);
    int* col       = (int*)p;    p += align256(sizeof(int) * E);
    double* gA     = (double*)p; p += align256(sizeof(double) * N * 8);
    double* gB     = (double*)p; p += align256(sizeof(double) * N * 8);
    float* xA[2]; float* xB[2]; float* xC[2];
    for (int s = 0; s < 2; ++s) {
        xA[s] = (float*)p; p += align256(sizeof(float) * N * 8);
        xB[s] = (float*)p; p += align256(sizeof(float) * N * 8);
        xC[s] = (float*)p; p += align256(sizeof(float) * N * 4);
    }

    const int BT = 256;
    int grid_n  = (N + BT - 1) / BT;
    int grid_e  = (E + BT - 1) / BT;
    int grid_nw = (N + 3) / 4;              // 1 wave per node, 4 waves per block
    int grid_ch = (SCAN_CHUNKS * 64 + BT - 1) / BT;   // 1 wave per chunk

    // ---- graph setup (identical work every call) ----
    (void)hipMemsetAsync(out_deg, 0, sizeof(int) * N, stream);
    (void)hipMemsetAsync(in_deg,  0, sizeof(int) * N, stream);
    count_deg<<<grid_e, BT, 0, stream>>>(src, dst, out_deg, in_deg, E);
    compute_norm<<<grid_n, BT, 0, stream>>>(out_deg, in_deg, dout_d, din_d, N);
    chunk_sums<<<grid_ch, BT, 0, stream>>>(in_deg, cs, N);
    scan_chunks<<<1, SCAN_CHUNKS, 0, stream>>>(cs);
    fill_rowptr<<<grid_ch, BT, 0, stream>>>(in_deg, cs, row_ptr, cursor, N, E);
    fill_csr<<<grid_e, BT, 0, stream>>>(src, dst, cursor, col, E);

    // ---- layer 0 (scalar input) ----
    compute_x0<<<grid_n, BT, 0, stream>>>(feat, dout_d, x0, N);
    layer_start<<<grid_nw, BT, 0, stream>>>(x0, row_ptr, col, din_d, dout_d,
                                            W_start, b_start, xA[0], xB[0], xC[0], N);

    // ---- 18 mid layers (ping-pong blocked x) ----
    int cur = 0;
    for (int l = 0; l < L; ++l) {
        const float* Wm = W_mid + (size_t)l * DH * DH;
        const float* bm = b_mid + (size_t)l * DH;
        gather8<<<grid_nw, BT, 0, stream>>>(xA[cur], row_ptr, col, gA, N);
        gather8<<<grid_nw, BT, 0, stream>>>(xB[cur], row_ptr, col, gB, N);
        gather4_matvec<<<grid_nw, BT, 0, stream>>>(xC[cur], row_ptr, col, gA, gB,
                                                   din_d, dout_d, Wm, bm,
                                                   xA[1 - cur], xB[1 - cur], xC[1 - cur],
                                                   (float*)d_out, N, 0);
        cur ^= 1;
    }

    // ---- final layer: raw store to d_out ----
    gather8<<<grid_nw, BT, 0, stream>>>(xA[cur], row_ptr, col, gA, N);
    gather8<<<grid_nw, BT, 0, stream>>>(xB[cur], row_ptr, col, gB, N);
    gather4_matvec<<<grid_nw, BT, 0, stream>>>(xC[cur], row_ptr, col, gA, gB,
                                               din_d, dout_d, W_final, b_final,
                                               xA[1 - cur], xB[1 - cur], xC[1 - cur],
                                               (float*)d_out, N, 1);
}

// Round 8
// 2864.688 us; speedup vs baseline: 1.8140x; 1.8140x over previous
//
#include <hip/hip_runtime.h>
#include <hip/hip_bf16.h>

#define DH 20            // hidden width
#define SCAN_CHUNKS 1024
#define LAYER_WAVES 8192 // persistent waves (2048 blocks x 4 waves)

// ---------------- setup kernels ----------------

// deg arrays are zeroed by hipMemsetAsync; counts EXCLUDE self-loop.
__global__ void count_deg(const int* __restrict__ src, const int* __restrict__ dst,
                          int* __restrict__ out_deg, int* __restrict__ in_deg, int E) {
    int e = blockIdx.x * blockDim.x + threadIdx.x;
    if (e < E) {
        atomicAdd(&out_deg[src[e]], 1);
        atomicAdd(&in_deg[dst[e]], 1);
    }
}

// norm = (deg+1)^-1/2  (self-loop included here)
__global__ void compute_norm(const int* __restrict__ out_deg, const int* __restrict__ in_deg,
                             double* __restrict__ dout, double* __restrict__ din, int n) {
    int i = blockIdx.x * blockDim.x + threadIdx.x;
    if (i < n) {
        dout[i] = 1.0 / sqrt((double)(out_deg[i] + 1));
        din[i]  = 1.0 / sqrt((double)(in_deg[i] + 1));
    }
}

// ---- parallel row_ptr build: chunk sums -> scan -> fill ----

__global__ void chunk_sums(const int* __restrict__ in_deg, int* __restrict__ cs, int n_nodes) {
    int w    = (blockIdx.x * blockDim.x + threadIdx.x) >> 6;   // wave = chunk
    int lane = threadIdx.x & 63;
    if (w >= SCAN_CHUNKS) return;
    int chunk = (n_nodes + SCAN_CHUNKS - 1) / SCAN_CHUNKS;
    int lo = w * chunk;
    int hi = lo + chunk; if (hi > n_nodes) hi = n_nodes;
    int s = 0;
    for (int i = lo + lane; i < hi; i += 64) s += in_deg[i];
#pragma unroll
    for (int off = 32; off; off >>= 1) s += __shfl_xor(s, off, 64);
    if (lane == 0) cs[w] = s;
}

__global__ void scan_chunks(int* __restrict__ cs) {
    __shared__ int lds[SCAN_CHUNKS];
    int t = threadIdx.x;
    int v = cs[t];
    lds[t] = v;
    __syncthreads();
    for (int off = 1; off < SCAN_CHUNKS; off <<= 1) {
        int u = (t >= off) ? lds[t - off] : 0;
        __syncthreads();
        lds[t] += u;
        __syncthreads();
    }
    cs[t] = lds[t] - v;   // exclusive prefix
}

__global__ void fill_rowptr(const int* __restrict__ in_deg, const int* __restrict__ cs,
                            int* __restrict__ row_ptr, int* __restrict__ cursor,
                            int n_nodes, int n_edges) {
    int w    = (blockIdx.x * blockDim.x + threadIdx.x) >> 6;   // wave = chunk
    int lane = threadIdx.x & 63;
    if (w >= SCAN_CHUNKS) return;
    int chunk = (n_nodes + SCAN_CHUNKS - 1) / SCAN_CHUNKS;
    int lo = w * chunk;
    int hi = lo + chunk; if (hi > n_nodes) hi = n_nodes;
    int run = cs[w];
    for (int base = lo; base < hi; base += 64) {
        int i = base + lane;
        int d = (i < hi) ? in_deg[i] : 0;
        int incl = d;
#pragma unroll
        for (int off = 1; off < 64; off <<= 1) {
            int t = __shfl_up(incl, off, 64);
            if (lane >= off) incl += t;
        }
        int excl = run + incl - d;
        if (i < hi) { row_ptr[i] = excl; cursor[i] = excl; }
        run += __shfl(incl, 63, 64);
    }
    if (w == 0 && lane == 0) row_ptr[n_nodes] = n_edges;
}

__global__ void fill_csr(const int* __restrict__ src, const int* __restrict__ dst,
                         int* __restrict__ cursor, int* __restrict__ col, int E) {
    int e = blockIdx.x * blockDim.x + threadIdx.x;
    if (e < E) {
        int slot = atomicAdd(&cursor[dst[e]], 1);
        col[slot] = src[e];
    }
}

// ---------------- layer kernels ----------------

// x0[n] = feat[n] * dout[n]   (layer 0 input is N x 1)
__global__ void compute_x0(const float* __restrict__ feat, const double* __restrict__ dout,
                           double* __restrict__ x0, int n) {
    int i = blockIdx.x * blockDim.x + threadIdx.x;
    if (i < n) x0[i] = (double)feat[i] * dout[i];
}

// layer 0: scalar gather, 64 lanes edge-parallel, one wave per node
__global__ __launch_bounds__(256) void layer_start(
        const double* __restrict__ x0, const int* __restrict__ row_ptr,
        const int* __restrict__ col, const double* __restrict__ din,
        const double* __restrict__ dout, const float* __restrict__ W,
        const float* __restrict__ b, float* __restrict__ xout, int n_nodes) {
    int n    = (blockIdx.x * blockDim.x + threadIdx.x) >> 6;
    int lane = threadIdx.x & 63;
    if (n >= n_nodes) return;
    double a = (lane == 0) ? x0[n] : 0.0;   // self loop
    int e0 = row_ptr[n], e1 = row_ptr[n + 1];
    for (int e = e0 + lane; e < e1; e += 64)
        a += x0[__builtin_nontemporal_load(&col[e])];
#pragma unroll
    for (int off = 32; off > 0; off >>= 1)
        a += __shfl_xor(a, off, 64);
    if (lane < DH) {
        double v = a * din[n] * (double)W[lane] + (double)b[lane];
        float r = fmaxf((float)v, 0.0f);
        xout[(long)n * DH + lane] = (float)((double)r * dout[n]);
    }
}

// mid/final layers: PERSISTENT waves, each owning a contiguous node range.
// Per node: lane = 5*ep + jq (ep<12 edge slot, jq<5 float4 quarter of the 80 B
// row). One coalesced col load covers 64 edges; shfl distributes; 4 predicated
// gathers cover 48 edges; rare deg>48 tail loops. The NEXT node's col block is
// prefetched before the current node's gathers are consumed (software pipeline),
// and row_ptr loads are chained (e0_next = e1_cur) so the col stream per wave
// is sequential.
__global__ __launch_bounds__(256, 8) void layer_fused(
        const float* __restrict__ x, const int* __restrict__ row_ptr,
        const int* __restrict__ col, const double* __restrict__ din,
        const double* __restrict__ dout, const float* __restrict__ W,
        const float* __restrict__ b, float* __restrict__ xout,
        int n_nodes, int npw, int mode) {
    __shared__ float Wl[DH * DH];
    for (int i = threadIdx.x; i < DH * DH; i += blockDim.x) Wl[i] = W[i];
    __syncthreads();

    int wv   = (blockIdx.x * blockDim.x + threadIdx.x) >> 6;
    int lane = threadIdx.x & 63;
    int n0 = wv * npw;
    int n1 = n0 + npw; if (n1 > n_nodes) n1 = n_nodes;
    if (n0 >= n1) return;

    int ep = lane / 5;            // edge slot 0..12 (lanes 60..63 inactive slots)
    int jq = lane - ep * 5;       // float4 quarter 0..4
    const float4* __restrict__ x4 = (const float4*)x;

    // prologue: col block for first node
    int e0 = row_ptr[n0], e1 = row_ptr[n0 + 1];
    int ci = (e0 + lane < e1) ? __builtin_nontemporal_load(&col[e0 + lane]) : -1;

    for (int n = n0; n < n1; ++n) {
        int ce0 = e0, ce1 = e1;
        int ci_cur = ci;
        // prefetch next node's col block (overlaps current node's gathers)
        if (n + 1 < n1) {
            e0 = e1;                              // rows are contiguous in CSR
            e1 = row_ptr[n + 2];
            ci = (e0 + lane < e1) ? __builtin_nontemporal_load(&col[e0 + lane]) : -1;
        }

        // distribute indices: slot ep takes positions ep, ep+12, ep+24, ep+36
        int s0 = __shfl(ci_cur, ep, 64);
        int s1 = __shfl(ci_cur, ep + 12, 64);
        int s2 = __shfl(ci_cur, ep + 24, 64);
        int s3 = __shfl(ci_cur, ep + 36, 64);
        bool p0 = (ep < 12) && (s0 >= 0);
        bool p1 = (ep < 12) && (s1 >= 0);
        bool p2 = (ep < 12) && (s2 >= 0);
        bool p3 = (ep < 12) && (s3 >= 0);

        float4 z = {0.0f, 0.0f, 0.0f, 0.0f};
        float4 v0 = z, v1 = z, v2 = z, v3 = z, vs = z;
        if (p0) v0 = x4[(size_t)s0 * 5 + jq];
        if (p1) v1 = x4[(size_t)s1 * 5 + jq];
        if (p2) v2 = x4[(size_t)s2 * 5 + jq];
        if (p3) v3 = x4[(size_t)s3 * 5 + jq];
        if (ep == 0) vs = x4[(size_t)n * 5 + jq];   // self loop on slot 0

        double g[4];
        g[0] = (double)vs.x + (double)v0.x + (double)v1.x + (double)v2.x + (double)v3.x;
        g[1] = (double)vs.y + (double)v0.y + (double)v1.y + (double)v2.y + (double)v3.y;
        g[2] = (double)vs.z + (double)v0.z + (double)v1.z + (double)v2.z + (double)v3.z;
        g[3] = (double)vs.w + (double)v0.w + (double)v1.w + (double)v2.w + (double)v3.w;

        // rare tail: deg > 48 (wave-uniform branch)
        if (ce1 - ce0 > 48) {
            if (ep < 12) {
                for (int e = ce0 + 48 + ep; e < ce1; e += 12) {
                    int s = __builtin_nontemporal_load(&col[e]);
                    float4 v = x4[(size_t)s * 5 + jq];
                    g[0] += (double)v.x; g[1] += (double)v.y;
                    g[2] += (double)v.z; g[3] += (double)v.w;
                }
            }
        }

        // fold 12 edge slots down to slot 0 (lanes 0..4 = quarters jq)
#define FOLD(LIM, DELTA)                                                        \
        {                                                                       \
            int srcl = lane + DELTA; if (srcl > 63) srcl = lane;                \
            double t0 = __shfl(g[0], srcl, 64);                                 \
            double t1 = __shfl(g[1], srcl, 64);                                 \
            double t2 = __shfl(g[2], srcl, 64);                                 \
            double t3 = __shfl(g[3], srcl, 64);                                 \
            if (ep < (LIM)) { g[0] += t0; g[1] += t1; g[2] += t2; g[3] += t3; } \
        }
        FOLD(4, 40)   // ep(0..3)  += ep+8
        FOLD(4, 20)   // ep(0..3)  += ep+4
        FOLD(2, 10)   // ep(0..1)  += ep+2
        FOLD(1, 5)    // ep(0)     += ep+1
#undef FOLD

        // cross-lane matvec: out_j = sum_k g_k W[k][j]; g_k at lane k>>2, reg k&3
        int jj = (lane < DH) ? lane : 0;
        double acc = 0.0;
#pragma unroll
        for (int k = 0; k < DH; ++k) {
            double gk = __shfl(g[k & 3], k >> 2, 64);
            acc += gk * (double)Wl[k * DH + jj];
        }

        if (lane < DH) {
            double v = acc * din[n] + (double)b[lane];
            if (mode == 0) {
                float r = fmaxf((float)v, 0.0f);
                xout[(size_t)n * DH + lane] = (float)((double)r * dout[n]);
            } else {
                xout[(size_t)n * DH + lane] = (float)v;
            }
        }
    }
}

// ---------------- launch ----------------

static inline size_t align256(size_t x) { return (x + 255) & ~(size_t)255; }

extern "C" void kernel_launch(void* const* d_in, const int* in_sizes, int n_in,
                              void* d_out, int out_size, void* d_ws, size_t ws_size,
                              hipStream_t stream) {
    const float* feat    = (const float*)d_in[0];
    const float* W_start = (const float*)d_in[1];
    const float* b_start = (const float*)d_in[2];
    const float* W_mid   = (const float*)d_in[3];
    const float* b_mid   = (const float*)d_in[4];
    const float* W_final = (const float*)d_in[5];
    const float* b_final = (const float*)d_in[6];
    const int*   src     = (const int*)d_in[7];
    const int*   dst     = (const int*)d_in[8];

    const int N = in_sizes[0];              // 100000
    const int E = in_sizes[7];              // 3200000
    const int L = in_sizes[3] / (DH * DH);  // 18 mid layers

    // workspace carve-up
    char* p = (char*)d_ws;
    double* dout_d = (double*)p; p += align256(sizeof(double) * N);
    double* din_d  = (double*)p; p += align256(sizeof(double) * N);
    double* x0     = (double*)p; p += align256(sizeof(double) * N);
    int* out_deg   = (int*)p;    p += align256(sizeof(int) * N);
    int* in_deg    = (int*)p;    p += align256(sizeof(int) * N);
    int* row_ptr   = (int*)p;    p += align256(sizeof(int) * (N + 1));
    int* cursor    = (int*)p;    p += align256(sizeof(int) * N);
    int* cs        = (int*)p;    p += align256(sizeof(int) * SCAN_CHUNKS);
    int* col       = (int*)p;    p += align256(sizeof(int) * E);
    float* xa      = (float*)p;  p += align256(sizeof(float) * N * DH);
    float* xb      = (float*)p;  p += align256(sizeof(float) * N * DH);

    const int BT = 256;
    int grid_n  = (N + BT - 1) / BT;
    int grid_e  = (E + BT - 1) / BT;
    int grid_nw = (N + 3) / 4;              // 1 wave per node (layer_start)
    int grid_ch = (SCAN_CHUNKS * 64 + BT - 1) / BT;
    int grid_pw = LAYER_WAVES / 4;          // persistent: 2048 blocks x 4 waves
    int npw     = (N + LAYER_WAVES - 1) / LAYER_WAVES;   // nodes per wave

    // ---- graph setup (identical work every call) ----
    (void)hipMemsetAsync(out_deg, 0, sizeof(int) * N, stream);
    (void)hipMemsetAsync(in_deg,  0, sizeof(int) * N, stream);
    count_deg<<<grid_e, BT, 0, stream>>>(src, dst, out_deg, in_deg, E);
    compute_norm<<<grid_n, BT, 0, stream>>>(out_deg, in_deg, dout_d, din_d, N);
    chunk_sums<<<grid_ch, BT, 0, stream>>>(in_deg, cs, N);
    scan_chunks<<<1, SCAN_CHUNKS, 0, stream>>>(cs);
    fill_rowptr<<<grid_ch, BT, 0, stream>>>(in_deg, cs, row_ptr, cursor, N, E);
    fill_csr<<<grid_e, BT, 0, stream>>>(src, dst, cursor, col, E);

    // ---- layer 0 (scalar input) ----
    compute_x0<<<grid_n, BT, 0, stream>>>(feat, dout_d, x0, N);
    layer_start<<<grid_nw, BT, 0, stream>>>(x0, row_ptr, col, din_d, dout_d,
                                            W_start, b_start, xa, N);

    // ---- 18 mid layers (ping-pong xa/xb) ----
    float* xin = xa;
    float* xot = xb;
    for (int l = 0; l < L; ++l) {
        layer_fused<<<grid_pw, BT, 0, stream>>>(xin, row_ptr, col, din_d, dout_d,
                                                W_mid + (size_t)l * DH * DH,
                                                b_mid + (size_t)l * DH, xot, N, npw, 0);
        float* t = xin; xin = xot; xot = t;
    }

    // ---- final layer: raw store to d_out ----
    layer_fused<<<grid_pw, BT, 0, stream>>>(xin, row_ptr, col, din_d, dout_d,
                                            W_final, b_final, (float*)d_out, N, npw, 1);
}